// Round 5
// baseline (151.831 us; speedup 1.0000x reference)
//
#include <hip/hip_runtime.h>
#include <math.h>

// (B,N,D,H) = (4, 2048, 1024, 64)
constexpr int kN = 2048;
constexpr int kD = 1024;

typedef __attribute__((ext_vector_type(8))) short bf16x8;
typedef __attribute__((ext_vector_type(4))) short bf16x4;
typedef __attribute__((ext_vector_type(4))) float f32x4;

#define MFMA(a, b, c) __builtin_amdgcn_mfma_f32_16x16x32_bf16(a, b, c, 0, 0, 0)

__device__ __forceinline__ short f2bf(float f) {
    unsigned u = __float_as_uint(f);
    u += 0x7fff + ((u >> 16) & 1);      // round-to-nearest-even
    return (short)(u >> 16);
}

// global->LDS direct DMA. LDS dest = wave-uniform base + lane*16.
__device__ __forceinline__ void g2l(void* lds, const void* g, int nbytes, int t) {
    int lane = t & 63, w = t >> 6;
    for (int base = w * 1024; base < nbytes; base += 4096) {
        if (base + lane * 16 < nbytes) {
            __builtin_amdgcn_global_load_lds(
                (const __attribute__((address_space(1))) void*)((const char*)g + base + lane * 16),
                (__attribute__((address_space(3))) void*)((char*)lds + base),
                16, 0, 0);
        }
    }
}

// ---------------------------------------------------------------------------
// prep: Wt[kc][192][72] = bf16(W^T) (pitch-72 g2l-ready tiles), bcat = bq|bk|bv
// ---------------------------------------------------------------------------
__global__ __launch_bounds__(256) void prep_kernel(
        const float* __restrict__ Wq, const float* __restrict__ Wk,
        const float* __restrict__ Wv, const float* __restrict__ bq,
        const float* __restrict__ bk, const float* __restrict__ bv,
        short* __restrict__ Wt, float* __restrict__ bcat)
{
    int tid = blockIdx.x * 256 + threadIdx.x;
    int stride = gridDim.x * 256;
    for (int e = tid; e < 16 * 192 * 72; e += stride) {
        int kc = e / (192 * 72);
        int rem = e - kc * (192 * 72);
        int n = rem / 72, c = rem - n * 72;
        short v = 0;
        if (c < 64) {
            int d = kc * 64 + c;
            float wv = (n < 64) ? Wq[d * 64 + n]
                     : (n < 128) ? Wk[d * 64 + (n - 64)]
                     : Wv[d * 64 + (n - 128)];
            v = f2bf(wv);
        }
        Wt[e] = v;
    }
    if (tid < 192)
        bcat[tid] = (tid < 64) ? bq[tid] : (tid < 128) ? bk[tid - 64] : bv[tid - 128];
}

// ---------------------------------------------------------------------------
// qkv: [8192x1024]@[1024x192]. 256 blocks x 32 rows (halves W re-staging vs
// M=16). Wave w = cols [48w,48w+48) x rows 32 (2x3 16-tiles). x loaded fp32
// direct (prefetch 2 deep), W double-buffered g2l.
// Outputs: gq/gk[8192][72] bf16, vt[(bz*32+jt)*64+h][72] bf16 (j-local cols).
// ---------------------------------------------------------------------------
__global__ __launch_bounds__(256) void qkv_kernel(
        const float* __restrict__ x, const short* __restrict__ Wt,
        const float* __restrict__ bcat,
        short* __restrict__ gq, short* __restrict__ gk, short* __restrict__ vt)
{
    __shared__ __align__(16) short xs[2][32 * 72];
    __shared__ __align__(16) short wsm[2][192 * 72];
    const int t = threadIdx.x;
    const int w = t >> 6, lane = t & 63, l15 = lane & 15, q8 = lane >> 4;
    const int m0 = blockIdx.x * 32;
    const int xrow = t >> 4, xc4 = t & 15;            // x stage: 2 rows/thread
    const float* xb0 = x + (size_t)(m0 + xrow) * kD + xc4 * 4;
    const float* xb1 = xb0 + 16 * kD;

    f32x4 acc[2][3];
    #pragma unroll
    for (int rt = 0; rt < 2; ++rt)
        #pragma unroll
        for (int ct = 0; ct < 3; ++ct) acc[rt][ct] = (f32x4){0.f, 0.f, 0.f, 0.f};

    // prologue
    float4 xc0 = *(const float4*)(xb0);
    float4 xc1 = *(const float4*)(xb1);
    g2l(wsm[0], Wt, 192 * 144, t);
    {
        bf16x4 p0 = {f2bf(xc0.x), f2bf(xc0.y), f2bf(xc0.z), f2bf(xc0.w)};
        bf16x4 p1 = {f2bf(xc1.x), f2bf(xc1.y), f2bf(xc1.z), f2bf(xc1.w)};
        *(bf16x4*)&xs[0][xrow * 72 + xc4 * 4] = p0;
        *(bf16x4*)&xs[0][(xrow + 16) * 72 + xc4 * 4] = p1;
    }
    float4 xn0 = *(const float4*)(xb0 + 64);
    float4 xn1 = *(const float4*)(xb1 + 64);
    __syncthreads();

    for (int kc = 0; kc < 16; ++kc) {
        const int cur = kc & 1, nb = cur ^ 1;
        if (kc < 15)
            g2l(wsm[nb], Wt + (size_t)(kc + 1) * 192 * 72, 192 * 144, t);

        bf16x8 a[2][2], b[3][2];
        #pragma unroll
        for (int rt = 0; rt < 2; ++rt) {
            int arow = rt * 16 + l15;
            a[rt][0] = *(const bf16x8*)&xs[cur][arow * 72 + q8 * 8];
            a[rt][1] = *(const bf16x8*)&xs[cur][arow * 72 + 32 + q8 * 8];
        }
        #pragma unroll
        for (int ct = 0; ct < 3; ++ct) {
            int brow = w * 48 + ct * 16 + l15;
            b[ct][0] = *(const bf16x8*)&wsm[cur][brow * 72 + q8 * 8];
            b[ct][1] = *(const bf16x8*)&wsm[cur][brow * 72 + 32 + q8 * 8];
        }
        #pragma unroll
        for (int rt = 0; rt < 2; ++rt)
            #pragma unroll
            for (int ct = 0; ct < 3; ++ct) {
                acc[rt][ct] = MFMA(a[rt][0], b[ct][0], acc[rt][ct]);
                acc[rt][ct] = MFMA(a[rt][1], b[ct][1], acc[rt][ct]);
            }
        if (kc < 15) {
            bf16x4 p0 = {f2bf(xn0.x), f2bf(xn0.y), f2bf(xn0.z), f2bf(xn0.w)};
            bf16x4 p1 = {f2bf(xn1.x), f2bf(xn1.y), f2bf(xn1.z), f2bf(xn1.w)};
            *(bf16x4*)&xs[nb][xrow * 72 + xc4 * 4] = p0;
            *(bf16x4*)&xs[nb][(xrow + 16) * 72 + xc4 * 4] = p1;
            if (kc < 14) {
                xn0 = *(const float4*)(xb0 + (kc + 2) * 64);
                xn1 = *(const float4*)(xb1 + (kc + 2) * 64);
            }
        }
        __syncthreads();
    }

    const int bz = m0 >> 11;
    const int jt = (m0 & 2047) >> 6;
    const int jb = m0 & 63;                // 0 or 32
    #pragma unroll
    for (int rt = 0; rt < 2; ++rt)
        #pragma unroll
        for (int ct = 0; ct < 3; ++ct) {
            int nb2 = w * 48 + ct * 16;    // 16-tile lies in one region
            int n = nb2 + l15;
            float bias = bcat[n];
            if (nb2 < 64) {
                #pragma unroll
                for (int r = 0; r < 4; ++r)
                    gq[(size_t)(m0 + rt * 16 + q8 * 4 + r) * 72 + n] =
                        f2bf(acc[rt][ct][r] + bias);
            } else if (nb2 < 128) {
                #pragma unroll
                for (int r = 0; r < 4; ++r)
                    gk[(size_t)(m0 + rt * 16 + q8 * 4 + r) * 72 + (n - 64)] =
                        f2bf(acc[rt][ct][r] + bias);
            } else {
                int h = n - 128;
                bf16x4 pk = {f2bf(acc[rt][ct][0] + bias), f2bf(acc[rt][ct][1] + bias),
                             f2bf(acc[rt][ct][2] + bias), f2bf(acc[rt][ct][3] + bias)};
                *(bf16x4*)&vt[((size_t)((bz * 32 + jt) * 64 + h)) * 72
                              + jb + rt * 16 + q8 * 4] = pk;
            }
        }
}

// ---------------------------------------------------------------------------
// stats: l[j] = sum_{i>=j, s!=0} exp(s/8). Double-buffered k tiles.
// Grid 512: b&3 = i-chunk(512), (b>>2)&3 = bz, b>>4 = j-tile(64). Max 8 iters.
// ---------------------------------------------------------------------------
__global__ __launch_bounds__(256) void stats_kernel(
        const short* __restrict__ gq, const short* __restrict__ gk,
        float* __restrict__ l2)
{
    __shared__ __align__(16) short qsm[64 * 72];
    __shared__ __align__(16) short ksm[2][64 * 72];
    const int t = threadIdx.x;
    const int w = t >> 6, lane = t & 63, l15 = lane & 15, q8 = lane >> 4;
    const int b = blockIdx.x;
    const int ic = b & 3, bz = (b >> 2) & 3, jt = b >> 4;
    const int j0 = jt * 64;
    const int ilo = ic * 512, ihi = ilo + 512;
    const int istart = (j0 > ilo) ? j0 : ilo;
    const int count = (istart < ihi) ? ((ihi - istart) >> 6) : 0;

    float lloc[4] = {0.f, 0.f, 0.f, 0.f};

    if (count > 0) {
        g2l(qsm, gq + (size_t)(bz * kN + j0) * 72, 64 * 144, t);
        g2l(ksm[0], gk + (size_t)(bz * kN + istart) * 72, 64 * 144, t);
        __syncthreads();
        int jrow = 16 * w + l15;
        bf16x8 a0 = *(const bf16x8*)&qsm[jrow * 72 + q8 * 8];
        bf16x8 a1 = *(const bf16x8*)&qsm[jrow * 72 + 32 + q8 * 8];

        for (int idx = 0; idx < count; ++idx) {
            const int cur = idx & 1;
            if (idx + 1 < count)
                g2l(ksm[cur ^ 1],
                    gk + (size_t)(bz * kN + istart + (idx + 1) * 64) * 72, 64 * 144, t);
            const int i0 = istart + idx * 64;
            #pragma unroll
            for (int it = 0; it < 4; ++it) {
                int irow = it * 16 + l15;
                bf16x8 b0 = *(const bf16x8*)&ksm[cur][irow * 72 + q8 * 8];
                bf16x8 b1 = *(const bf16x8*)&ksm[cur][irow * 72 + 32 + q8 * 8];
                f32x4 s = (f32x4){0.f, 0.f, 0.f, 0.f};
                s = MFMA(a0, b0, s);
                s = MFMA(a1, b1, s);
                int ig = i0 + it * 16 + l15;
                #pragma unroll
                for (int r = 0; r < 4; ++r) {
                    int jg = j0 + 16 * w + q8 * 4 + r;
                    float sv = s[r];
                    float e = __expf(sv * 0.125f);
                    lloc[r] += ((ig >= jg) && (sv != 0.0f)) ? e : 0.0f;
                }
            }
            __syncthreads();
        }
    }
    #pragma unroll
    for (int off = 1; off < 16; off <<= 1)
        #pragma unroll
        for (int r = 0; r < 4; ++r)
            lloc[r] += __shfl_xor(lloc[r], off);
    if (l15 == 0) {
        #pragma unroll
        for (int r = 0; r < 4; ++r)
            l2[ic * 8192 + bz * kN + j0 + 16 * w + q8 * 4 + r] = lloc[r];
    }
}

// ---------------------------------------------------------------------------
// out: partial[i,h] = sum_{j-half, j<=i} exp(s/8)*(1/l[j])*v[j,h]
// Grid 256: b&1 = half s, (b>>1)&3 = bz, b>>3 = i-tile. Balanced split:
// i-tile it has it+1 j-tiles; s=0 takes first ceil((it+1)/2), s=1 the rest
// (both <= 16 iters). S recomputed with bit-identical MFMA sequence as stats.
// ---------------------------------------------------------------------------
__global__ __launch_bounds__(256) void out_kernel(
        const short* __restrict__ gq, const short* __restrict__ gk,
        const short* __restrict__ vt, const float* __restrict__ l2,
        float* __restrict__ part)
{
    __shared__ __align__(16) short ksm[64 * 72];
    __shared__ __align__(16) short qsm[2][64 * 72];
    __shared__ __align__(16) short vsm[2][64 * 72];
    __shared__ __align__(16) short psm[64 * 72];
    __shared__ float rsm[2][64];
    const int t = threadIdx.x;
    const int w = t >> 6, lane = t & 63, l15 = lane & 15, q8 = lane >> 4;
    const int b = blockIdx.x;
    const int s = b & 1, bz = (b >> 1) & 3, it = b >> 3;
    const int i0 = it * 64;
    const int h0 = (it + 2) >> 1;                  // ceil((it+1)/2)
    const int count = s == 0 ? h0 : (it + 1 - h0); // <= 16
    const int jlo = s == 0 ? 0 : h0 * 64;

    f32x4 oacc[4];
    #pragma unroll
    for (int i = 0; i < 4; ++i) oacc[i] = (f32x4){0.f, 0.f, 0.f, 0.f};

    if (count > 0) {
        g2l(ksm, gk + (size_t)(bz * kN + i0) * 72, 64 * 144, t);
        g2l(qsm[0], gq + (size_t)(bz * kN + jlo) * 72, 64 * 144, t);
        g2l(vsm[0], vt + (size_t)((bz * 32 + (jlo >> 6)) * 64) * 72, 64 * 144, t);
        if (t < 64) {
            int j = bz * kN + jlo + t;
            float l = l2[j] + l2[8192 + j] + l2[16384 + j] + l2[24576 + j];
            rsm[0][t] = (l > 0.f) ? 1.0f / l : 0.0f;
        }
        __syncthreads();

        for (int idx = 0; idx < count; ++idx) {
            const int cur = idx & 1, nb = cur ^ 1;
            const int j0s = jlo + idx * 64;
            if (idx + 1 < count) {
                g2l(qsm[nb], gq + (size_t)(bz * kN + j0s + 64) * 72, 64 * 144, t);
                g2l(vsm[nb], vt + (size_t)((bz * 32 + ((j0s + 64) >> 6)) * 64) * 72,
                    64 * 144, t);
                if (t < 64) {
                    int j = bz * kN + j0s + 64 + t;
                    float l = l2[j] + l2[8192 + j] + l2[16384 + j] + l2[24576 + j];
                    rsm[nb][t] = (l > 0.f) ? 1.0f / l : 0.0f;
                }
            }
            // S phase (identical sequence to stats)
            int jrow = 16 * w + l15;
            bf16x8 a0 = *(const bf16x8*)&qsm[cur][jrow * 72 + q8 * 8];
            bf16x8 a1 = *(const bf16x8*)&qsm[cur][jrow * 72 + 32 + q8 * 8];
            #pragma unroll
            for (int itile = 0; itile < 4; ++itile) {
                int irow = itile * 16 + l15;
                bf16x8 b0 = *(const bf16x8*)&ksm[irow * 72 + q8 * 8];
                bf16x8 b1 = *(const bf16x8*)&ksm[irow * 72 + 32 + q8 * 8];
                f32x4 sv4 = (f32x4){0.f, 0.f, 0.f, 0.f};
                sv4 = MFMA(a0, b0, sv4);
                sv4 = MFMA(a1, b1, sv4);
                int ig = i0 + itile * 16 + l15;
                bf16x4 pk;
                #pragma unroll
                for (int r = 0; r < 4; ++r) {
                    int jl = 16 * w + q8 * 4 + r;
                    int jg = j0s + jl;
                    float sv = sv4[r];
                    float p = ((ig >= jg) && (sv != 0.0f))
                            ? __expf(sv * 0.125f) * rsm[cur][jl] : 0.0f;
                    pk[r] = f2bf(p);
                }
                *(bf16x4*)&psm[(itile * 16 + l15) * 72 + 16 * w + q8 * 4] = pk;
            }
            __syncthreads();   // psm ready; next-tile g2l had S-phase to fly

            // PV phase: A = psm[i-local][j], B = vsm[h][j]
            bf16x8 pa0 = *(const bf16x8*)&psm[(16 * w + l15) * 72 + q8 * 8];
            bf16x8 pa1 = *(const bf16x8*)&psm[(16 * w + l15) * 72 + 32 + q8 * 8];
            #pragma unroll
            for (int ht = 0; ht < 4; ++ht) {
                int vrow = ht * 16 + l15;
                bf16x8 vb0 = *(const bf16x8*)&vsm[cur][vrow * 72 + q8 * 8];
                bf16x8 vb1 = *(const bf16x8*)&vsm[cur][vrow * 72 + 32 + q8 * 8];
                oacc[ht] = MFMA(pa0, vb0, oacc[ht]);
                oacc[ht] = MFMA(pa1, vb1, oacc[ht]);
            }
            __syncthreads();   // protect psm + qsm[cur]/vsm[cur] for next iter
        }
    }
    size_t base = ((size_t)(s * 4 + bz) * kN + i0) * 64;
    #pragma unroll
    for (int ht = 0; ht < 4; ++ht)
        #pragma unroll
        for (int r = 0; r < 4; ++r)
            part[base + (size_t)(16 * w + q8 * 4 + r) * 64 + ht * 16 + l15] = oacc[ht][r];
}

// ---------------------------------------------------------------------------
// reduce: out = part_half0 + part_half1
// ---------------------------------------------------------------------------
__global__ __launch_bounds__(256) void reduce_kernel(
        const float* __restrict__ part, float* __restrict__ out)
{
    int idx = blockIdx.x * 256 + threadIdx.x;     // 0..131071 float4s
    const float4* p = (const float4*)part;
    float4 a = p[idx];
    float4 b = p[idx + 131072];
    float4 r;
    r.x = a.x + b.x;
    r.y = a.y + b.y;
    r.z = a.z + b.z;
    r.w = a.w + b.w;
    ((float4*)out)[idx] = r;
}

extern "C" void kernel_launch(void* const* d_in, const int* in_sizes, int n_in,
                              void* d_out, int out_size, void* d_ws, size_t ws_size,
                              hipStream_t stream)
{
    const float* x  = (const float*)d_in[0];
    const float* Wq = (const float*)d_in[1];
    const float* bq = (const float*)d_in[2];
    const float* Wk = (const float*)d_in[3];
    const float* bk = (const float*)d_in[4];
    const float* Wv = (const float*)d_in[5];
    const float* bv = (const float*)d_in[6];
    float* out = (float*)d_out;

    char* base = (char*)d_ws;
    short* Wt   = (short*)(base);                    //    442,368 B
    float* bcat = (float*)(base + 442368);           //      1,024 B
    short* gq   = (short*)(base + 443392);           //  1,179,648 B
    short* gk   = (short*)(base + 1623040);          //  1,179,648 B
    short* vt   = (short*)(base + 2802688);          //  1,179,648 B
    float* l2   = (float*)(base + 3982336);          //    131,072 B
    float* part = (float*)(base + 4113408);          //  4,194,304 B (~8.3 MB total)

    prep_kernel<<<128, 256, 0, stream>>>(Wq, Wk, Wv, bq, bk, bv, Wt, bcat);
    qkv_kernel<<<256, 256, 0, stream>>>(x, Wt, bcat, gq, gk, vt);
    stats_kernel<<<512, 256, 0, stream>>>(gq, gk, l2);
    out_kernel<<<256, 256, 0, stream>>>(gq, gk, vt, l2, part);
    reduce_kernel<<<512, 256, 0, stream>>>(part, out);
}